// Round 7
// baseline (77.599 us; speedup 1.0000x reference)
//
#include <hip/hip_runtime.h>
#include <hip/hip_bf16.h>

#define NB 4096

typedef short v8s __attribute__((ext_vector_type(8)));
typedef float v4f __attribute__((ext_vector_type(4)));

// ws layout: part[4096*16] float2 (512 KB) | sq[4096] f32 (16 KB) | xb (1 MB)
// xb layout: row-major 128 bf16/row, 16-chunk XOR swizzle: chunk c of row r
// stored at chunk position c^(r&15). DMA-compatible (contiguous rows) AND
// conflict-floor fragment reads.

__device__ __forceinline__ void dma16(const unsigned short* g, unsigned short* l) {
    __builtin_amdgcn_global_load_lds(
        (const __attribute__((address_space(1))) unsigned int*)g,
        (__attribute__((address_space(3))) unsigned int*)l, 16, 0, 0);
}

__global__ __launch_bounds__(256) void prep_kernel(const float* __restrict__ x,
        float* __restrict__ sq, unsigned short* __restrict__ xb,
        float* __restrict__ out) {
    int tid = threadIdx.x;
    int row = blockIdx.x * 8 + (tid >> 5);
    int lane = tid & 31;
    const float4* xg = (const float4*)x;
    float4 v = xg[row * 32 + lane];            // elements k = 4*lane..+3
    __hip_bfloat16 h0 = __float2bfloat16(v.x), h1 = __float2bfloat16(v.y);
    __hip_bfloat16 h2 = __float2bfloat16(v.z), h3 = __float2bfloat16(v.w);
    ushort4 u4;
    u4.x = *(unsigned short*)&h0; u4.y = *(unsigned short*)&h1;
    u4.z = *(unsigned short*)&h2; u4.w = *(unsigned short*)&h3;
    int c = lane >> 1, half = lane & 1;        // 8-element chunk, which half
    int p = c ^ (row & 15);                    // swizzled chunk position
    *(ushort4*)&xb[(size_t)row * 128 + p * 8 + half * 4] = u4;
    // sq from bf16-rounded values (consistent with MFMA dot -> diag dist == 0)
    float f0 = __bfloat162float(h0), f1 = __bfloat162float(h1);
    float f2 = __bfloat162float(h2), f3 = __bfloat162float(h3);
    float s = f0 * f0 + f1 * f1 + f2 * f2 + f3 * f3;
    #pragma unroll
    for (int off = 16; off > 0; off >>= 1) s += __shfl_down(s, off);
    if (lane == 0) sq[row] = s;
    if (blockIdx.x == 0 && tid == 0) out[0] = 0.f;
}

// 512 blocks (2/CU, ONE residency round), 256 threads. Block = i-panel x 2
// j-tiles; A staged once via DMA; B restaged between j-tiles.
__global__ __launch_bounds__(256) void snn_mfma(const unsigned short* __restrict__ xb,
        const int* __restrict__ y, const float* __restrict__ sqg,
        float2* __restrict__ part) {
    __shared__ __align__(16) unsigned short At[128 * 128];   // 32 KB, swizzled rows
    __shared__ __align__(16) unsigned short Bt[128 * 128];   // 32 KB
    __shared__ float2 red[2][128];
    __shared__ float sqi[128], sqj[128];
    __shared__ int yi[128], yj[128];

    const int tid = threadIdx.x;
    const int w = tid >> 6, lane = tid & 63;
    const int wm = w >> 1, wn = w & 1;         // 64x64 wave tile
    const int lr = lane & 15, q = lane >> 4;
    const int i0 = blockIdx.x * 128;
    const int jt0 = blockIdx.y * 2;            // first of 2 j-tiles

    // stage A + B(jt0): each DMA inst = 4 rows (64 lanes x 16 B), LDS dst uniform
    #pragma unroll
    for (int r = 0; r < 8; ++r) {
        int row = w * 32 + r * 4;
        dma16(xb + (size_t)(i0 + row) * 128 + lane * 8, &At[row * 128]);
        dma16(xb + (size_t)(jt0 * 128 + row) * 128 + lane * 8, &Bt[row * 128]);
    }
    if (tid < 128) { sqi[tid] = sqg[i0 + tid]; yi[tid] = y[i0 + tid]; }
    else { int c = tid - 128; sqj[c] = sqg[jt0 * 128 + c]; yj[c] = y[jt0 * 128 + c]; }
    __syncthreads();   // vmcnt drain publishes DMA data

    const float c1 = 0.014426950408889634f;    // log2(e)/100
    const float c2 = 0.028853900817778936f;    // 2*c1
    float nsum[4][4], dsum[4][4];
    #pragma unroll
    for (int mt = 0; mt < 4; ++mt)
        #pragma unroll
        for (int r = 0; r < 4; ++r) { nsum[mt][r] = 0.f; dsum[mt][r] = 0.f; }

    #pragma unroll
    for (int jt = 0; jt < 2; ++jt) {
        v4f acc[4][4];
        #pragma unroll
        for (int mt = 0; mt < 4; ++mt)
            #pragma unroll
            for (int nt = 0; nt < 4; ++nt)
                #pragma unroll
                for (int r = 0; r < 4; ++r) acc[mt][nt][r] = 0.f;

        #pragma unroll
        for (int kk = 0; kk < 4; ++kk) {
            v8s af[4], bf[4];
            #pragma unroll
            for (int mt = 0; mt < 4; ++mt) {
                int row = wm * 64 + mt * 16 + lr;
                af[mt] = *(const v8s*)&At[row * 128 + (((kk * 4 + q) ^ lr) * 8)];
            }
            #pragma unroll
            for (int nt = 0; nt < 4; ++nt) {
                int row = wn * 64 + nt * 16 + lr;
                bf[nt] = *(const v8s*)&Bt[row * 128 + (((kk * 4 + q) ^ lr) * 8)];
            }
            #pragma unroll
            for (int mt = 0; mt < 4; ++mt)
                #pragma unroll
                for (int nt = 0; nt < 4; ++nt)
                    acc[mt][nt] = __builtin_amdgcn_mfma_f32_16x16x32_bf16(
                        af[mt], bf[nt], acc[mt][nt], 0, 0, 0);
        }

        // epilogue for this j-tile
        int jbase = (jt0 + jt) * 128;
        float bj[4]; int yj_r[4], jcol[4];
        #pragma unroll
        for (int nt = 0; nt < 4; ++nt) {
            int jc = wn * 64 + nt * 16 + lr;
            bj[nt] = -c1 * sqj[jc]; yj_r[nt] = yj[jc]; jcol[nt] = jbase + jc;
        }
        #pragma unroll
        for (int mt = 0; mt < 4; ++mt) {
            #pragma unroll
            for (int r = 0; r < 4; ++r) {
                int rloc = wm * 64 + mt * 16 + q * 4 + r;   // C/D: row = q*4+reg
                float bi = -c1 * sqi[rloc];
                int yir = yi[rloc], ig = i0 + rloc;
                float n = 0.f, d = 0.f;
                #pragma unroll
                for (int nt = 0; nt < 4; ++nt) {
                    float arg = fminf(0.f, fmaf(acc[mt][nt][r], c2, bi + bj[nt]));
                    float e = __builtin_amdgcn_exp2f(arg);
                    d += e;
                    bool ok = (yir == yj_r[nt]) && (ig != jcol[nt]);
                    n += ok ? e : 0.f;
                }
                n += __shfl_xor(n, 1); d += __shfl_xor(d, 1);
                n += __shfl_xor(n, 2); d += __shfl_xor(d, 2);
                n += __shfl_xor(n, 4); d += __shfl_xor(d, 4);
                n += __shfl_xor(n, 8); d += __shfl_xor(d, 8);
                nsum[mt][r] += n; dsum[mt][r] += d;
            }
        }

        if (jt == 0) {   // restage B for the second j-tile
            __syncthreads();   // all reads of Bt / sqj / yj complete
            #pragma unroll
            for (int r = 0; r < 8; ++r) {
                int row = w * 32 + r * 4;
                dma16(xb + (size_t)((jt0 + 1) * 128 + row) * 128 + lane * 8,
                      &Bt[row * 128]);
            }
            if (tid >= 128) {
                int c = tid - 128;
                sqj[c] = sqg[(jt0 + 1) * 128 + c]; yj[c] = y[(jt0 + 1) * 128 + c];
            }
            __syncthreads();
        }
    }

    #pragma unroll
    for (int mt = 0; mt < 4; ++mt)
        #pragma unroll
        for (int r = 0; r < 4; ++r)
            if (lr == 0)
                red[wn][wm * 64 + mt * 16 + q * 4 + r] =
                    make_float2(nsum[mt][r], dsum[mt][r]);
    __syncthreads();

    if (tid < 128) {
        float2 a = red[0][tid], b = red[1][tid];
        part[(size_t)(i0 + tid) * 16 + blockIdx.y] = make_float2(a.x + b.x, a.y + b.y);
    }
}

__global__ __launch_bounds__(256) void snn_final(const float2* __restrict__ part,
        float* __restrict__ out) {
    __shared__ float wsum[4];
    int row = blockIdx.x * 256 + threadIdx.x;
    const float4* p = (const float4*)&part[(size_t)row * 16];
    float n = 0.f, d = 0.f;
    #pragma unroll
    for (int c = 0; c < 8; ++c) {
        float4 v = p[c];
        n += v.x + v.z; d += v.y + v.w;
    }
    float l = __logf(d) - __logf(n);
    #pragma unroll
    for (int off = 32; off > 0; off >>= 1) l += __shfl_down(l, off);
    int wid = threadIdx.x >> 6;
    if ((threadIdx.x & 63) == 0) wsum[wid] = l;
    __syncthreads();
    if (threadIdx.x == 0) {
        float s = wsum[0] + wsum[1] + wsum[2] + wsum[3];
        atomicAdd(out, s * (1.0f / NB));
    }
}

extern "C" void kernel_launch(void* const* d_in, const int* in_sizes, int n_in,
                              void* d_out, int out_size, void* d_ws, size_t ws_size,
                              hipStream_t stream) {
    const float* x = (const float*)d_in[0];
    const int*   y = (const int*)d_in[1];
    float* out = (float*)d_out;
    float2* part = (float2*)d_ws;                                   // 512 KB
    float* sq = (float*)((char*)d_ws + (512 << 10));                // 16 KB
    unsigned short* xb = (unsigned short*)((char*)d_ws + (512 << 10) + (16 << 10));

    prep_kernel<<<NB / 8, 256, 0, stream>>>(x, sq, xb, out);
    dim3 grid(NB / 128, NB / 256);   // 32 i-panels x 16 j-groups = 512 blocks
    snn_mfma<<<grid, 256, 0, stream>>>(xb, y, sq, part);
    snn_final<<<NB / 256, 256, 0, stream>>>(part, out);
}